// Round 1
// baseline (178.916 us; speedup 1.0000x reference)
//
#include <hip/hip_runtime.h>

#define BATCH 64
#define SEQ   512
#define JDIM  96
#define TN    64
#define KC    64
#define NCH   (SEQ / KC)
#define LDB   72   // bf16 row stride: 144 B = 16B-aligned, 2-way banks on frag reads (free)

typedef __attribute__((ext_vector_type(8))) short bf16x8;
typedef __attribute__((ext_vector_type(4))) float f32x4;

#define LOG2D (-0.32192809489f)   // log2(0.8)

// exact RNE float->bf16 (finite inputs)
__device__ __forceinline__ unsigned short f2bf(float f) {
  unsigned u = __float_as_uint(f);
  u += 0x7FFFu + ((u >> 16) & 1u);
  return (unsigned short)(u >> 16);
}

// ---------------- T1: xT[j][b*SEQ+m] = bf16(x[b][m][j])
__global__ __launch_bounds__(256) void transpose_in_kernel(
    const float* __restrict__ x, unsigned short* __restrict__ xT) {
  __shared__ float tile[JDIM * 65];  // [j][rr]
  const int r0 = blockIdx.x * 64;    // 512 blocks cover R = 32768 rows
  const int R = BATCH * SEQ;
  for (int idx = threadIdx.x; idx < 64 * 24; idx += 256) {
    int rr = idx / 24, jg = idx - rr * 24;
    float4 v = *(const float4*)(x + (size_t)(r0 + rr) * JDIM + 4 * jg);
    tile[(4 * jg + 0) * 65 + rr] = v.x;
    tile[(4 * jg + 1) * 65 + rr] = v.y;
    tile[(4 * jg + 2) * 65 + rr] = v.z;
    tile[(4 * jg + 3) * 65 + rr] = v.w;
  }
  __syncthreads();
  for (int idx = threadIdx.x; idx < JDIM * 8; idx += 256) {
    int jj = idx >> 3, rg = idx & 7;
    const float* t = &tile[jj * 65 + 8 * rg];
    uint4 pk;
    pk.x = (unsigned)f2bf(t[0]) | ((unsigned)f2bf(t[1]) << 16);
    pk.y = (unsigned)f2bf(t[2]) | ((unsigned)f2bf(t[3]) << 16);
    pk.z = (unsigned)f2bf(t[4]) | ((unsigned)f2bf(t[5]) << 16);
    pk.w = (unsigned)f2bf(t[6]) | ((unsigned)f2bf(t[7]) << 16);
    *(uint4*)(&xT[(size_t)jj * R + r0 + 8 * rg]) = pk;
  }
}

// ---------------- Fused: per block (j, n-tile 64): C[64b x 64n] = X_j * exp(pre+off)^T, /L.
// R3 structure: register-prefetch of next chunk's global loads (off HBM latency hidden
// under current chunk's exp+MFMA), double-buffered LDS with ONE barrier per chunk,
// and exp2 ladder (1 exp2f per float4 of pre instead of 4).
__global__ __launch_bounds__(256, 3) void fused_kernel(
    const unsigned short* __restrict__ xT,  // [J][B*SEQ] bf16
    const float* __restrict__ off,          // [J][SEQ][SEQ]
    float* __restrict__ outT) {             // [J][SEQ][B]
  __shared__ unsigned short As[2][BATCH * LDB];  // [buf][b][k] k-contiguous
  __shared__ unsigned short Bs[2][TN * LDB];     // [buf][n][k] k-contiguous
  __shared__ float Lred[TN * 17];
  __shared__ float Linv[TN];

  const int j  = blockIdx.x >> 3;           // 8 consecutive blocks share j (xT L2/L3 reuse)
  const int n0 = (blockIdx.x & 7) * TN;

  const int tid  = threadIdx.x;
  const int lane = tid & 63;
  const int wid  = tid >> 6;      // 4 waves
  const int ln   = lane & 15;
  const int quad = lane >> 4;
  const int bw   = (wid & 1) * 32;
  const int nw   = (wid >> 1) * 32;

  f32x4 acc[2][2];
#pragma unroll
  for (int i = 0; i < 2; ++i)
#pragma unroll
    for (int q = 0; q < 2; ++q) acc[i][q] = (f32x4){0.f, 0.f, 0.f, 0.f};
  float Lpart[4] = {0.f, 0.f, 0.f, 0.f};

  const unsigned short* xTj = xT + (size_t)j * (BATCH * SEQ);
  const float* offj = off + (size_t)j * (SEQ * SEQ);

  const int a_kg = tid & 7;    // 8 groups x 8 bf16 per KC row
  const int a_b  = tid >> 3;   // 0..31 (+32)
  const int b_mg = tid & 15;   // k-group of 4 floats
  const int b_n  = tid >> 4;   // 0..15 (4 passes)

  // per-row normalizer c_n = 0.2 / (1 - 0.8^(n+1)) for this thread's 4 n-rows
  float cn[4];
#pragma unroll
  for (int p = 0; p < 4; ++p) {
    const int n = n0 + b_n + 16 * p;
    cn[p] = 0.2f / (1.0f - exp2f(LOG2D * (float)(n + 1)));
  }

  // register prefetch state (one chunk's worth of global loads)
  uint4  va[2];
  float4 vo[4];

#define LOADCH(CH) do {                                                          \
    const int m0_ = (CH) * KC;                                                   \
    va[0] = *(const uint4*)(xTj + (size_t)a_b * SEQ + m0_ + 8 * a_kg);           \
    va[1] = *(const uint4*)(xTj + (size_t)(a_b + 32) * SEQ + m0_ + 8 * a_kg);    \
    _Pragma("unroll")                                                            \
    for (int p = 0; p < 4; ++p)                                                  \
      vo[p] = *(const float4*)(offj + (size_t)(n0 + b_n + 16 * p) * SEQ + m0_ + 4 * b_mg); \
  } while (0)

#define STAGECH(BUF, CH) do {                                                    \
    const int m0_ = (CH) * KC;                                                   \
    *(uint4*)(&As[BUF][a_b * LDB + 8 * a_kg]) = va[0];                           \
    *(uint4*)(&As[BUF][(a_b + 32) * LDB + 8 * a_kg]) = va[1];                    \
    const int mbase = m0_ + 4 * b_mg;                                            \
    _Pragma("unroll")                                                            \
    for (int p = 0; p < 4; ++p) {                                                \
      const int nl = b_n + 16 * p;                                               \
      const int n  = n0 + nl;                                                    \
      const float4 o = vo[p];                                                    \
      const float cc = cn[p];                                                    \
      const float d0 = (float)(n - mbase);                                       \
      /* pre ladder: pb = cc*0.8^d0; 0.8^(d0-k) = pb * 1.25^k (inf when d0<<0, masked) */ \
      const float pb = cc * exp2f(LOG2D * d0);                                   \
      const float p0 = (d0 >= 0.f) ? pb : 0.f;                                   \
      const float p1 = (d0 >= 1.f) ? pb * 1.25f : 0.f;                           \
      const float p2 = (d0 >= 2.f) ? pb * 1.5625f : 0.f;                         \
      const float p3 = (d0 >= 3.f) ? pb * 1.953125f : 0.f;                       \
      const float e0 = __expf(o.x + p0);                                         \
      const float e1 = __expf(o.y + p1);                                         \
      const float e2 = __expf(o.z + p2);                                         \
      const float e3 = __expf(o.w + p3);                                         \
      Lpart[p] += (e0 + e1) + (e2 + e3);                                         \
      uint2 pk;                                                                  \
      pk.x = (unsigned)f2bf(e0) | ((unsigned)f2bf(e1) << 16);                    \
      pk.y = (unsigned)f2bf(e2) | ((unsigned)f2bf(e3) << 16);                    \
      *(uint2*)(&Bs[BUF][nl * LDB + 4 * b_mg]) = pk;                             \
    }                                                                            \
  } while (0)

  // prologue: stage chunk 0, prefetch chunk 1
  LOADCH(0);
  STAGECH(0, 0);
  LOADCH(1);
  __syncthreads();

  int c = 0;
#pragma unroll
  for (int ch = 0; ch < NCH; ++ch) {
    // MFMA on buf c (ready since last barrier); staging below touches only buf c^1
#pragma unroll
    for (int ks = 0; ks < KC; ks += 32) {
      bf16x8 afrag[2], bfrag[2];
#pragma unroll
      for (int i = 0; i < 2; ++i)
        afrag[i] = *(const bf16x8*)(&As[c][(bw + 16 * i + ln) * LDB + ks + 8 * quad]);
#pragma unroll
      for (int q = 0; q < 2; ++q)
        bfrag[q] = *(const bf16x8*)(&Bs[c][(nw + 16 * q + ln) * LDB + ks + 8 * quad]);
#pragma unroll
      for (int i = 0; i < 2; ++i)
#pragma unroll
        for (int q = 0; q < 2; ++q)
          acc[i][q] = __builtin_amdgcn_mfma_f32_16x16x32_bf16(afrag[i], bfrag[q], acc[i][q], 0, 0, 0);
    }
    if (ch + 1 < NCH) STAGECH(c ^ 1, ch + 1);   // consumes prefetched regs (chunk ch+1)
    if (ch + 2 < NCH) LOADCH(ch + 2);           // issue next loads; land during next chunk
    __syncthreads();                            // buf c^1 staged; buf c reads all done
    c ^= 1;
  }
#undef LOADCH
#undef STAGECH

  // reduce L across the 16 k-group partials per row
#pragma unroll
  for (int p = 0; p < 4; ++p) Lred[(b_n + 16 * p) * 17 + b_mg] = Lpart[p];
  __syncthreads();
  if (tid < TN) {
    float s = 0.f;
#pragma unroll
    for (int i = 0; i < 16; ++i) s += Lred[tid * 17 + i];
    Linv[tid] = 1.0f / s;
  }
  __syncthreads();

  // epilogue: C/D layout col(=n)=lane&15, row(=b)=quad*4+reg -> float4 along b
  float* outTj = outT + (size_t)j * (SEQ * BATCH);
#pragma unroll
  for (int q = 0; q < 2; ++q) {
    const int nc = nw + 16 * q + ln;
    const float linv = Linv[nc];
#pragma unroll
    for (int i = 0; i < 2; ++i) {
      float4 v;
      v.x = acc[i][q][0] * linv;
      v.y = acc[i][q][1] * linv;
      v.z = acc[i][q][2] * linv;
      v.w = acc[i][q][3] * linv;
      *(float4*)(&outTj[(size_t)(n0 + nc) * BATCH + bw + 16 * i + 4 * quad]) = v;
    }
  }
}

// ---------------- T2: out[b][n][j] = outT[j][n][b]
__global__ __launch_bounds__(256) void transpose_out_kernel(
    const float* __restrict__ outT, float* __restrict__ out) {
  __shared__ float tile[JDIM * 65];  // [j][b]
  const int n = blockIdx.x;          // 512 blocks
  for (int idx = threadIdx.x; idx < JDIM * 16; idx += 256) {
    int jj = idx >> 4, g = idx & 15;
    float4 v = *(const float4*)(outT + ((size_t)jj * SEQ + n) * BATCH + 4 * g);
    float* t = &tile[jj * 65 + 4 * g];
    t[0] = v.x; t[1] = v.y; t[2] = v.z; t[3] = v.w;
  }
  __syncthreads();
  for (int idx = threadIdx.x; idx < BATCH * 24; idx += 256) {
    int b = idx / 24, jg = idx - b * 24;
    float4 w;
    w.x = tile[(4 * jg + 0) * 65 + b];
    w.y = tile[(4 * jg + 1) * 65 + b];
    w.z = tile[(4 * jg + 2) * 65 + b];
    w.w = tile[(4 * jg + 3) * 65 + b];
    *(float4*)(out + ((size_t)b * SEQ + n) * JDIM + 4 * jg) = w;
  }
}

extern "C" void kernel_launch(void* const* d_in, const int* in_sizes, int n_in,
                              void* d_out, int out_size, void* d_ws, size_t ws_size,
                              hipStream_t stream) {
  const float* x   = (const float*)d_in[0];  // [64, 512, 96]
  const float* off = (const float*)d_in[1];  // [96, 512, 512]
  float* out = (float*)d_out;                // [64, 512, 96]

  unsigned short* xT = (unsigned short*)d_ws;                 // bf16 [96][64*512] = 6.29 MB
  float* outT = (float*)((char*)d_ws + (size_t)JDIM * BATCH * SEQ * sizeof(unsigned short));
                                                              // f32 [96][512][64] = 12.58 MB

  transpose_in_kernel<<<BATCH * SEQ / 64, 256, 0, stream>>>(x, xT);
  fused_kernel<<<JDIM * (SEQ / TN), 256, 0, stream>>>(xT, off, outT);
  transpose_out_kernel<<<SEQ, 256, 0, stream>>>(outT, out);
}

// Round 2
// 173.328 us; speedup vs baseline: 1.0322x; 1.0322x over previous
//
#include <hip/hip_runtime.h>

#define BATCH 64
#define SEQ   512
#define JDIM  96
#define TN    64
#define KC    64
#define NCH   (SEQ / KC)
#define LDB   72   // bf16 row stride: 144 B = 16B-aligned, 2-way banks on frag reads (free)

typedef __attribute__((ext_vector_type(8))) short bf16x8;
typedef __attribute__((ext_vector_type(4))) float f32x4;

#define LOG2D (-0.32192809489f)   // log2(0.8)

// exact RNE float->bf16 (finite inputs)
__device__ __forceinline__ unsigned short f2bf(float f) {
  unsigned u = __float_as_uint(f);
  u += 0x7FFFu + ((u >> 16) & 1u);
  return (unsigned short)(u >> 16);
}

// ---------------- T1: xT[j][b*SEQ+m] = bf16(x[b][m][j])
__global__ __launch_bounds__(256) void transpose_in_kernel(
    const float* __restrict__ x, unsigned short* __restrict__ xT) {
  __shared__ float tile[JDIM * 65];  // [j][rr]
  const int r0 = blockIdx.x * 64;    // 512 blocks cover R = 32768 rows
  const int R = BATCH * SEQ;
  for (int idx = threadIdx.x; idx < 64 * 24; idx += 256) {
    int rr = idx / 24, jg = idx - rr * 24;
    float4 v = *(const float4*)(x + (size_t)(r0 + rr) * JDIM + 4 * jg);
    tile[(4 * jg + 0) * 65 + rr] = v.x;
    tile[(4 * jg + 1) * 65 + rr] = v.y;
    tile[(4 * jg + 2) * 65 + rr] = v.z;
    tile[(4 * jg + 3) * 65 + rr] = v.w;
  }
  __syncthreads();
  for (int idx = threadIdx.x; idx < JDIM * 8; idx += 256) {
    int jj = idx >> 3, rg = idx & 7;
    const float* t = &tile[jj * 65 + 8 * rg];
    uint4 pk;
    pk.x = (unsigned)f2bf(t[0]) | ((unsigned)f2bf(t[1]) << 16);
    pk.y = (unsigned)f2bf(t[2]) | ((unsigned)f2bf(t[3]) << 16);
    pk.z = (unsigned)f2bf(t[4]) | ((unsigned)f2bf(t[5]) << 16);
    pk.w = (unsigned)f2bf(t[6]) | ((unsigned)f2bf(t[7]) << 16);
    *(uint4*)(&xT[(size_t)jj * R + r0 + 8 * rg]) = pk;
  }
}

// ---------------- Fused: per block (j, n-tile 64): C[64b x 64n] = X_j * exp(pre+off)^T, /L.
// R4: raw s_barrier with lgkmcnt-only drain (prefetched global loads stay in flight
// across the chunk barrier — __syncthreads was draining vmcnt(0) and killing the R3
// pipeline), plus 4 blocks/CU (LDS trimmed to 36 KB by aliasing Lred/Linv into As).
__global__ __launch_bounds__(256, 4) void fused_kernel(
    const unsigned short* __restrict__ xT,  // [J][B*SEQ] bf16
    const float* __restrict__ off,          // [J][SEQ][SEQ]
    float* __restrict__ outT) {             // [J][SEQ][B]
  __shared__ unsigned short As[2][BATCH * LDB];  // [buf][b][k] k-contiguous
  __shared__ unsigned short Bs[2][TN * LDB];     // [buf][n][k] k-contiguous
  // Lred/Linv alias the As space (only live after the main loop).
  float* Lred = (float*)&As[0][0];       // TN*17 floats = 4352 B
  float* Linv = Lred + TN * 17;          // +256 B; total 4608 B << 18432 B of As[0]

  const int j  = blockIdx.x >> 3;           // 8 consecutive blocks share j (xT L2/L3 reuse)
  const int n0 = (blockIdx.x & 7) * TN;

  const int tid  = threadIdx.x;
  const int lane = tid & 63;
  const int wid  = tid >> 6;      // 4 waves
  const int ln   = lane & 15;
  const int quad = lane >> 4;
  const int bw   = (wid & 1) * 32;
  const int nw   = (wid >> 1) * 32;

  f32x4 acc[2][2];
#pragma unroll
  for (int i = 0; i < 2; ++i)
#pragma unroll
    for (int q = 0; q < 2; ++q) acc[i][q] = (f32x4){0.f, 0.f, 0.f, 0.f};
  float Lpart[4] = {0.f, 0.f, 0.f, 0.f};

  const unsigned short* xTj = xT + (size_t)j * (BATCH * SEQ);
  const float* offj = off + (size_t)j * (SEQ * SEQ);

  const int a_kg = tid & 7;    // 8 groups x 8 bf16 per KC row
  const int a_b  = tid >> 3;   // 0..31 (+32)
  const int b_mg = tid & 15;   // k-group of 4 floats
  const int b_n  = tid >> 4;   // 0..15 (4 passes)

  // per-row normalizer c_n = 0.2 / (1 - 0.8^(n+1)) for this thread's 4 n-rows
  float cn[4];
#pragma unroll
  for (int p = 0; p < 4; ++p) {
    const int n = n0 + b_n + 16 * p;
    cn[p] = 0.2f / (1.0f - exp2f(LOG2D * (float)(n + 1)));
  }

  // register prefetch state (one chunk's worth of global loads)
  uint4  va[2];
  float4 vo[4];

#define LOADCH(CH) do {                                                          \
    const int m0_ = (CH) * KC;                                                   \
    va[0] = *(const uint4*)(xTj + (size_t)a_b * SEQ + m0_ + 8 * a_kg);           \
    va[1] = *(const uint4*)(xTj + (size_t)(a_b + 32) * SEQ + m0_ + 8 * a_kg);    \
    _Pragma("unroll")                                                            \
    for (int p = 0; p < 4; ++p)                                                  \
      vo[p] = *(const float4*)(offj + (size_t)(n0 + b_n + 16 * p) * SEQ + m0_ + 4 * b_mg); \
  } while (0)

#define STAGECH(BUF, CH) do {                                                    \
    const int m0_ = (CH) * KC;                                                   \
    *(uint4*)(&As[BUF][a_b * LDB + 8 * a_kg]) = va[0];                           \
    *(uint4*)(&As[BUF][(a_b + 32) * LDB + 8 * a_kg]) = va[1];                    \
    const int mbase = m0_ + 4 * b_mg;                                            \
    _Pragma("unroll")                                                            \
    for (int p = 0; p < 4; ++p) {                                                \
      const int nl = b_n + 16 * p;                                               \
      const int n  = n0 + nl;                                                    \
      const float4 o = vo[p];                                                    \
      const float cc = cn[p];                                                    \
      const float d0 = (float)(n - mbase);                                       \
      /* pre ladder: pb = cc*0.8^d0; 0.8^(d0-k) = pb * 1.25^k (inf when d0<<0, masked) */ \
      const float pb = cc * exp2f(LOG2D * d0);                                   \
      const float p0 = (d0 >= 0.f) ? pb : 0.f;                                   \
      const float p1 = (d0 >= 1.f) ? pb * 1.25f : 0.f;                           \
      const float p2 = (d0 >= 2.f) ? pb * 1.5625f : 0.f;                         \
      const float p3 = (d0 >= 3.f) ? pb * 1.953125f : 0.f;                       \
      const float e0 = __expf(o.x + p0);                                         \
      const float e1 = __expf(o.y + p1);                                         \
      const float e2 = __expf(o.z + p2);                                         \
      const float e3 = __expf(o.w + p3);                                         \
      Lpart[p] += (e0 + e1) + (e2 + e3);                                         \
      uint2 pk;                                                                  \
      pk.x = (unsigned)f2bf(e0) | ((unsigned)f2bf(e1) << 16);                    \
      pk.y = (unsigned)f2bf(e2) | ((unsigned)f2bf(e3) << 16);                    \
      *(uint2*)(&Bs[BUF][nl * LDB + 4 * b_mg]) = pk;                             \
    }                                                                            \
  } while (0)

  // Chunk barrier: order LDS ops only; do NOT drain vmcnt — prefetched global
  // loads stay in flight across the barrier (the whole point of R4).
#define CHUNK_BARRIER() do {                                                     \
    __builtin_amdgcn_sched_barrier(0);                                           \
    asm volatile("s_waitcnt lgkmcnt(0)" ::: "memory");                           \
    __builtin_amdgcn_s_barrier();                                                \
    __builtin_amdgcn_sched_barrier(0);                                           \
  } while (0)

  // prologue: stage chunk 0, prefetch chunk 1
  LOADCH(0);
  STAGECH(0, 0);
  LOADCH(1);
  CHUNK_BARRIER();

  int c = 0;
#pragma unroll
  for (int ch = 0; ch < NCH; ++ch) {
    // MFMA on buf c (ready since last barrier); staging below touches only buf c^1
#pragma unroll
    for (int ks = 0; ks < KC; ks += 32) {
      bf16x8 afrag[2], bfrag[2];
#pragma unroll
      for (int i = 0; i < 2; ++i)
        afrag[i] = *(const bf16x8*)(&As[c][(bw + 16 * i + ln) * LDB + ks + 8 * quad]);
#pragma unroll
      for (int q = 0; q < 2; ++q)
        bfrag[q] = *(const bf16x8*)(&Bs[c][(nw + 16 * q + ln) * LDB + ks + 8 * quad]);
#pragma unroll
      for (int i = 0; i < 2; ++i)
#pragma unroll
        for (int q = 0; q < 2; ++q)
          acc[i][q] = __builtin_amdgcn_mfma_f32_16x16x32_bf16(afrag[i], bfrag[q], acc[i][q], 0, 0, 0);
    }
    if (ch + 1 < NCH) STAGECH(c ^ 1, ch + 1);   // consumes prefetched regs (vmcnt wait lands here)
    if (ch + 2 < NCH) LOADCH(ch + 2);           // issue next loads; they cross the barrier in flight
    CHUNK_BARRIER();                            // lgkm drain only
    c ^= 1;
  }
#undef LOADCH
#undef STAGECH
#undef CHUNK_BARRIER

  // reduce L across the 16 k-group partials per row (Lred aliases As; all As
  // ds_reads were lgkm-drained before the final chunk barrier)
#pragma unroll
  for (int p = 0; p < 4; ++p) Lred[(b_n + 16 * p) * 17 + b_mg] = Lpart[p];
  __syncthreads();
  if (tid < TN) {
    float s = 0.f;
#pragma unroll
    for (int i = 0; i < 16; ++i) s += Lred[tid * 17 + i];
    Linv[tid] = 1.0f / s;
  }
  __syncthreads();

  // epilogue: C/D layout col(=n)=lane&15, row(=b)=quad*4+reg -> float4 along b
  float* outTj = outT + (size_t)j * (SEQ * BATCH);
#pragma unroll
  for (int q = 0; q < 2; ++q) {
    const int nc = nw + 16 * q + ln;
    const float linv = Linv[nc];
#pragma unroll
    for (int i = 0; i < 2; ++i) {
      float4 v;
      v.x = acc[i][q][0] * linv;
      v.y = acc[i][q][1] * linv;
      v.z = acc[i][q][2] * linv;
      v.w = acc[i][q][3] * linv;
      *(float4*)(&outTj[(size_t)(n0 + nc) * BATCH + bw + 16 * i + 4 * quad]) = v;
    }
  }
}

// ---------------- T2: out[b][n][j] = outT[j][n][b]
__global__ __launch_bounds__(256) void transpose_out_kernel(
    const float* __restrict__ outT, float* __restrict__ out) {
  __shared__ float tile[JDIM * 65];  // [j][b]
  const int n = blockIdx.x;          // 512 blocks
  for (int idx = threadIdx.x; idx < JDIM * 16; idx += 256) {
    int jj = idx >> 4, g = idx & 15;
    float4 v = *(const float4*)(outT + ((size_t)jj * SEQ + n) * BATCH + 4 * g);
    float* t = &tile[jj * 65 + 4 * g];
    t[0] = v.x; t[1] = v.y; t[2] = v.z; t[3] = v.w;
  }
  __syncthreads();
  for (int idx = threadIdx.x; idx < BATCH * 24; idx += 256) {
    int b = idx / 24, jg = idx - b * 24;
    float4 w;
    w.x = tile[(4 * jg + 0) * 65 + b];
    w.y = tile[(4 * jg + 1) * 65 + b];
    w.z = tile[(4 * jg + 2) * 65 + b];
    w.w = tile[(4 * jg + 3) * 65 + b];
    *(float4*)(out + ((size_t)b * SEQ + n) * JDIM + 4 * jg) = w;
  }
}

extern "C" void kernel_launch(void* const* d_in, const int* in_sizes, int n_in,
                              void* d_out, int out_size, void* d_ws, size_t ws_size,
                              hipStream_t stream) {
  const float* x   = (const float*)d_in[0];  // [64, 512, 96]
  const float* off = (const float*)d_in[1];  // [96, 512, 512]
  float* out = (float*)d_out;                // [64, 512, 96]

  unsigned short* xT = (unsigned short*)d_ws;                 // bf16 [96][64*512] = 6.29 MB
  float* outT = (float*)((char*)d_ws + (size_t)JDIM * BATCH * SEQ * sizeof(unsigned short));
                                                              // f32 [96][512][64] = 12.58 MB

  transpose_in_kernel<<<BATCH * SEQ / 64, 256, 0, stream>>>(x, xT);
  fused_kernel<<<JDIM * (SEQ / TN), 256, 0, stream>>>(xT, off, outT);
  transpose_out_kernel<<<SEQ, 256, 0, stream>>>(outT, out);
}